// Round 4
// baseline (2767.719 us; speedup 1.0000x reference)
//
#include <hip/hip_runtime.h>
#include <hip/hip_bf16.h>
#include <cstdint>
#include <cstddef>

#define HP 320   // padded hidden/N dim (300 -> 320)

typedef unsigned short ushortT;
typedef __attribute__((ext_vector_type(8))) __bf16 bf16x8;
typedef __attribute__((ext_vector_type(4))) float f32x4;

__device__ __forceinline__ float b2f(unsigned u) {
    union { unsigned i; float f; } v; v.i = u << 16; return v.f;
}
__device__ __forceinline__ ushortT f2b(float f) {
    union { float f; unsigned i; } v; v.f = f;
    unsigned x = v.i;
    return (ushortT)((x + 0x7fffu + ((x >> 16) & 1u)) >> 16);
}
__device__ __forceinline__ unsigned subpk(unsigned a, unsigned r) {
    union { unsigned i; float f; } al, ah, rl, rh;
    al.i = a << 16; ah.i = a & 0xffff0000u;
    rl.i = r << 16; rh.i = r & 0xffff0000u;
    float lo = al.f - rl.f, hi = ah.f - rh.f;
    return (unsigned)f2b(lo) | ((unsigned)f2b(hi) << 16);
}
__device__ __forceinline__ uint4 subpk4(uint4 a, uint4 r) {
    uint4 o;
    o.x = subpk(a.x, r.x); o.y = subpk(a.y, r.y);
    o.z = subpk(a.z, r.z); o.w = subpk(a.w, r.w);
    return o;
}

// ---------------------------------------------------------------- pack weights into MFMA B-fragment order
// packed[kt][nt(20)][kg(4)][col(16)][j(8)]  ==  W[kt*32+kg*8+j][nt*16+col]
__device__ __forceinline__ void pack_one(int idx, const float* __restrict__ W,
                                         int Ksrc, ushortT* __restrict__ dst) {
    int j = idx & 7, col = (idx >> 3) & 15, kg = (idx >> 7) & 3;
    int t = idx >> 9; int nt = t % 20, kt = t / 20;
    int k = kt * 32 + kg * 8 + j, n = nt * 16 + col;
    float v = (k < Ksrc && n < 300) ? W[k * 300 + n] : 0.f;
    dst[idx] = f2b(v);
}
// W_o remap: logical k<133 -> fa rows (src k), k in [160,460) -> amsg rows (src k-27), else 0
__device__ __forceinline__ void pack_wo(int idx, const float* __restrict__ W,
                                        ushortT* __restrict__ dst) {
    int j = idx & 7, col = (idx >> 3) & 15, kg = (idx >> 7) & 3;
    int t = idx >> 9; int nt = t % 20, kt = t / 20;
    int k = kt * 32 + kg * 8 + j, n = nt * 16 + col;
    int src = (k < 133) ? k : ((k >= 160 && k < 460) ? (k - 27) : -1);
    float v = (src >= 0 && n < 300) ? W[src * 300 + n] : 0.f;
    dst[idx] = f2b(v);
}

__global__ __launch_bounds__(256) void k_pack_weights(
    const float* __restrict__ Wi, const float* __restrict__ Wh,
    const float* __restrict__ Wo, const float* __restrict__ bo,
    ushortT* __restrict__ Wipk, ushortT* __restrict__ Whpk,
    ushortT* __restrict__ Wopk, float* __restrict__ bop) {
    int idx = blockIdx.x * 256 + threadIdx.x;
    if (idx < 51200)  pack_one(idx, Wi, 147, Wipk);   // K1 = 160 (5 ktiles)
    if (idx < 102400) pack_one(idx, Wh, 300, Whpk);   // K2 = 320 (10 ktiles)
    if (idx < 153600) pack_wo(idx, Wo, Wopk);         // K3 = 480 (15 ktiles)
    if (idx < HP) bop[idx] = (idx < 300) ? bo[idx] : 0.f;
}

// ---------------------------------------------------------------- pre-pack f_bonds -> bf16 [nB][160]
__global__ __launch_bounds__(256) void k_pack_fb(
    const float* __restrict__ fb, ushortT* __restrict__ fbb, int nB) {
    int t = blockIdx.x * 256 + threadIdx.x;
    if (t >= nB * 20) return;
    int row = t / 20, q = t - row * 20;
    int k0 = q * 8;
    union { ushortT u[8]; uint4 v; } o;
#pragma unroll
    for (int j = 0; j < 8; j++) {
        int k = k0 + j;
        o.u[j] = (k < 147) ? f2b(fb[(size_t)row * 147 + k]) : (ushortT)0;
    }
    *(uint4*)(fbb + (size_t)row * 160 + k0) = o.v;
}

// ---------------------------------------------------------------- unified MFMA GEMM (always "compact": recompute inp)
// MODE 0: A = f_bonds (K=160, 5 kt).                      out: msg = relu(acc)
// MODE 1: A = amsg[b2a]-msg[b2revb] (10 kt) then f_bonds recompute (5 kt).  out: msg = relu(acc)
// MODE 2: A = fa (5 kt) | amsg (10 kt).                   out: ah fp32 = relu(acc + bias)
template <int MODE, bool FBB>
__global__ __launch_bounds__(256) void k_mfma(
    const float* __restrict__ fa, const float* __restrict__ fb,
    const ushortT* __restrict__ fbb,
    const ushortT* __restrict__ amsg, const ushortT* __restrict__ msgin,
    const int* __restrict__ b2a, const int* __restrict__ b2revb,
    const ushortT* __restrict__ Wpk, const ushortT* __restrict__ Wipk,
    const float* __restrict__ bop,
    ushortT* __restrict__ msgout, float* __restrict__ ahout) {
    __shared__ __align__(16) char smem[24576];
    ushortT* A_lds = (ushortT*)smem;            // [kg(4)][row(64)][j(8)]  4 KB
    ushortT* B_lds = (ushortT*)(smem + 4096);   // [nt(20)][kg(4)][col(16)][j(8)] 20 KB
    const int tid = threadIdx.x, wave = tid >> 6, lane = tid & 63;
    const int row0 = blockIdx.x * 64;
    const int wm = wave >> 1, wn = wave & 1;

    size_t offa = 0, offr = 0;
    if (MODE == 1) {
        offa = (size_t)b2a[row0 + lane] * HP;     // lane == gathered row
        offr = (size_t)b2revb[row0 + lane] * HP;
    }

    f32x4 acc[2][10];
#pragma unroll
    for (int i = 0; i < 2; i++)
#pragma unroll
        for (int n = 0; n < 10; n++) acc[i][n] = (f32x4){0.f, 0.f, 0.f, 0.f};

    const int TOT = (MODE == 0) ? 5 : 15;

    uint4 ua, ur;
    uint4 breg[5];

    auto load_fbrow = [&](int k0) -> uint4 {
        if (FBB) {
            return *(const uint4*)(fbb + (size_t)(row0 + lane) * 160 + k0);
        } else {
            union { ushortT u[8]; uint4 v; } t;
#pragma unroll
            for (int j = 0; j < 8; j++) {
                int k = k0 + j;
                t.u[j] = (k < 147) ? f2b(fb[(size_t)(row0 + lane) * 147 + k]) : (ushortT)0;
            }
            return t.v;
        }
    };
    auto load_tile = [&](int kts) {
        const ushortT* Bsrc;
        int kt;
        if (MODE == 1 && kts >= 10) { kt = kts - 10; Bsrc = Wipk; }
        else                        { kt = kts;      Bsrc = Wpk;  }
        const int k0 = kt * 32 + wave * 8;
        if (MODE == 1) {
            if (kts < 10) {
                ua = *(const uint4*)(amsg + offa + k0);
                ur = *(const uint4*)(msgin + offr + k0);
            } else {
                ua = load_fbrow(k0);
            }
        } else if (MODE == 2) {
            if (kt >= 5) {
                ua = *(const uint4*)(amsg + (size_t)(row0 + lane) * HP + (k0 - 160));
            } else {
                union { ushortT u[8]; uint4 v; } t;
#pragma unroll
                for (int j = 0; j < 8; j++) {
                    int k = k0 + j;
                    t.u[j] = (k < 133) ? f2b(fa[(size_t)(row0 + lane) * 133 + k]) : (ushortT)0;
                }
                ua = t.v;
            }
        } else {
            ua = load_fbrow(k0);
        }
        const uint4* bp = (const uint4*)(Bsrc + (size_t)kt * 10240);
#pragma unroll
        for (int i = 0; i < 5; i++) breg[i] = bp[tid + 256 * i];
    };

    load_tile(0);
    for (int kts = 0; kts < TOT; kts++) {
        __syncthreads();   // previous iter's LDS reads done
        uint4 aw = (MODE == 1 && kts < 10) ? subpk4(ua, ur) : ua;
        *(uint4*)&A_lds[wave * 512 + lane * 8] = aw;
#pragma unroll
        for (int i = 0; i < 5; i++) ((uint4*)B_lds)[tid + 256 * i] = breg[i];
        __syncthreads();
        if (kts + 1 < TOT) load_tile(kts + 1);   // prefetch under compute
        bf16x8 a0 = *(bf16x8*)&A_lds[(lane >> 4) * 512 + (wm * 32 + (lane & 15)) * 8];
        bf16x8 a1 = *(bf16x8*)&A_lds[(lane >> 4) * 512 + (wm * 32 + 16 + (lane & 15)) * 8];
#pragma unroll
        for (int n = 0; n < 10; n++) {
            bf16x8 b = *(bf16x8*)&B_lds[(wn * 10 + n) * 512 + (lane >> 4) * 128 + (lane & 15) * 8];
            acc[0][n] = __builtin_amdgcn_mfma_f32_16x16x32_bf16(a0, b, acc[0][n], 0, 0, 0);
            acc[1][n] = __builtin_amdgcn_mfma_f32_16x16x32_bf16(a1, b, acc[1][n], 0, 0, 0);
        }
    }

    // ---- staged, coalesced epilogue. C frag: col=lane&15, row=(lane>>4)*4+reg.
    // XOR-swizzle col by g(<<4) (g = inter-lane row group) to avoid 4-way bank conflicts.
    if (MODE == 2) {
        float* Cf = (float*)smem;   // [16][HP] fp32, 20 KB per pass
#pragma unroll
        for (int p = 0; p < 4; p++) {            // pass p = (wm, i) pair, rows [p*16, p*16+16)
            __syncthreads();
            if (wm == (p >> 1)) {
                const int i = p & 1;
                const int g = (lane >> 4) & 3;
                const int rb = g * 4;
#pragma unroll
                for (int n = 0; n < 10; n++) {
                    int col = wn * 160 + n * 16 + (lane & 15);
                    int colx = col ^ (g << 4);
#pragma unroll
                    for (int r = 0; r < 4; r++) {
                        float v = acc[i][n][r] + bop[col];
                        Cf[(rb + r) * HP + colx] = fmaxf(v, 0.f);
                    }
                }
            }
            __syncthreads();
#pragma unroll
            for (int i5 = 0; i5 < 5; i5++) {
                int flat = tid + 256 * i5;        // < 1280 = 16 rows * 80 chunks
                int rl = flat / 80, ch = flat - rl * 80;
                int colx = (ch * 4) ^ (((rl >> 2) & 3) << 4);
                uint4 v = *(uint4*)&Cf[rl * HP + colx];
                *(uint4*)&ahout[(size_t)(row0 + p * 16 + rl) * HP + ch * 4] = v;
            }
        }
    } else {
        ushortT* C = (ushortT*)smem;  // [32][HP] bf16, 20 KB per pass
#pragma unroll
        for (int p = 0; p < 2; p++) {            // pass p = wm, rows [p*32, p*32+32)
            __syncthreads();
            if (wm == p) {
#pragma unroll
                for (int i = 0; i < 2; i++) {
                    const int g = (lane >> 4) & 3;
                    const int rb = i * 16 + g * 4;
#pragma unroll
                    for (int n = 0; n < 10; n++) {
                        int col = wn * 160 + n * 16 + (lane & 15);
                        int colx = col ^ (g << 4);
#pragma unroll
                        for (int r = 0; r < 4; r++)
                            C[(rb + r) * HP + colx] = f2b(fmaxf(acc[i][n][r], 0.f));
                    }
                }
            }
            __syncthreads();
#pragma unroll
            for (int i5 = 0; i5 < 5; i5++) {
                int flat = tid + 256 * i5;        // < 1280 = 32 rows * 40 chunks
                int rl = flat / 40, ch = flat - rl * 40;
                int colx = (ch * 8) ^ (((rl >> 2) & 3) << 4);
                uint4 v = *(uint4*)&C[rl * HP + colx];
                *(uint4*)&msgout[(size_t)(row0 + p * 32 + rl) * HP + ch * 8] = v;
            }
        }
    }
}

// ---------------------------------------------------------------- atom sum (bf16 in/out, fp32 accum)
__global__ __launch_bounds__(256) void k_atom_sum(
    const ushortT* __restrict__ msg, const int* __restrict__ a2b,
    ushortT* __restrict__ amsg, int nA) {
    int t = blockIdx.x * 256 + threadIdx.x;
    int a = t / 40, q = t - a * 40;
    if (a >= nA) return;
    float s[8];
#pragma unroll
    for (int e = 0; e < 8; e++) s[e] = 0.f;
#pragma unroll
    for (int j = 0; j < 6; j++) {
        int b = a2b[a * 6 + j];
        uint4 u = *(const uint4*)(msg + (size_t)b * HP + q * 8);
        s[0] += b2f(u.x & 0xffff); s[1] += b2f(u.x >> 16);
        s[2] += b2f(u.y & 0xffff); s[3] += b2f(u.y >> 16);
        s[4] += b2f(u.z & 0xffff); s[5] += b2f(u.z >> 16);
        s[6] += b2f(u.w & 0xffff); s[7] += b2f(u.w >> 16);
    }
    uint4 o;
    o.x = (unsigned)f2b(s[0]) | ((unsigned)f2b(s[1]) << 16);
    o.y = (unsigned)f2b(s[2]) | ((unsigned)f2b(s[3]) << 16);
    o.z = (unsigned)f2b(s[4]) | ((unsigned)f2b(s[5]) << 16);
    o.w = (unsigned)f2b(s[6]) | ((unsigned)f2b(s[7]) << 16);
    *(uint4*)(amsg + (size_t)a * HP + q * 8) = o;
}

// ---------------------------------------------------------------- mean pool
__global__ __launch_bounds__(256) void k_pool(
    const float* __restrict__ ah, float* __restrict__ out, int n_mols, int apm) {
    int t = blockIdx.x * 256 + threadIdx.x;
    if (t >= n_mols * 300) return;
    int m = t / 300, h = t - m * 300;
    const float* p = ah + (size_t)m * apm * HP + h;
    float s = 0.f;
    for (int u = 0; u < apm; u++) s += p[(size_t)u * HP];
    out[t] = s * (1.0f / (float)apm);
}

// ---------------------------------------------------------------- launch
extern "C" void kernel_launch(void* const* d_in, const int* in_sizes, int n_in,
                              void* d_out, int out_size, void* d_ws, size_t ws_size,
                              hipStream_t stream) {
    const float* fa     = (const float*)d_in[0];
    const float* fb     = (const float*)d_in[1];
    const int*   a2b    = (const int*)d_in[2];
    const int*   b2a    = (const int*)d_in[3];
    const int*   b2revb = (const int*)d_in[4];
    const float* Wi     = (const float*)d_in[5];
    const float* Wh     = (const float*)d_in[6];
    const float* Wo     = (const float*)d_in[7];
    const float* bo     = (const float*)d_in[8];

    const int nA     = in_sizes[0] / 133;   // 200000
    const int nB     = in_sizes[1] / 147;   // 400000
    const int n_mols = out_size / 300;      // 10000
    const int apm    = nA / n_mols;         // 20

    char* p = (char*)d_ws;
    ushortT* Wipk = (ushortT*)p;  p += (size_t)51200 * 2;
    ushortT* Whpk = (ushortT*)p;  p += (size_t)102400 * 2;
    ushortT* Wopk = (ushortT*)p;  p += (size_t)153600 * 2;
    float*   bop  = (float*)p;    p += (size_t)HP * 4;
    p = (char*)(((uintptr_t)p + 255) & ~(uintptr_t)255);

    const size_t msgBytes  = (size_t)nB * HP * 2;
    const size_t amsgBytes = (size_t)nA * HP * 2;
    const size_t fbbBytes  = (size_t)nB * 160 * 2;
    const size_t headBytes = (size_t)(p - (char*)d_ws);
    const bool use_fbb = ws_size >= headBytes + 2 * msgBytes + amsgBytes + fbbBytes;

    ushortT* msgA = (ushortT*)p;  p += msgBytes;
    ushortT* msgB = (ushortT*)p;  p += msgBytes;
    ushortT* amsg = (ushortT*)p;  p += amsgBytes;
    ushortT* fbb  = use_fbb ? (ushortT*)p : nullptr;
    float*   ah   = (float*)msgB;   // msgB dead after depth-2 GEMM reads it
    float*   out  = (float*)d_out;

    k_pack_weights<<<600, 256, 0, stream>>>(Wi, Wh, Wo, bo, Wipk, Whpk, Wopk, bop);
    if (use_fbb)
        k_pack_fb<<<(nB * 20 + 255) / 256, 256, 0, stream>>>(fb, fbb, nB);

    const int asum_grid = (int)(((size_t)nA * 40 + 255) / 256);

    // GEMM1: msgA = relu(fb @ Wi)
    if (use_fbb)
        k_mfma<0, true ><<<nB / 64, 256, 0, stream>>>(fa, fb, fbb, nullptr, nullptr, nullptr, nullptr,
                                                      Wipk, Wipk, bop, msgA, nullptr);
    else
        k_mfma<0, false><<<nB / 64, 256, 0, stream>>>(fa, fb, fbb, nullptr, nullptr, nullptr, nullptr,
                                                      Wipk, Wipk, bop, msgA, nullptr);

    // depth 1: msgA -> msgB
    k_atom_sum<<<asum_grid, 256, 0, stream>>>(msgA, a2b, amsg, nA);
    if (use_fbb)
        k_mfma<1, true ><<<nB / 64, 256, 0, stream>>>(fa, fb, fbb, amsg, msgA, b2a, b2revb,
                                                      Whpk, Wipk, bop, msgB, nullptr);
    else
        k_mfma<1, false><<<nB / 64, 256, 0, stream>>>(fa, fb, fbb, amsg, msgA, b2a, b2revb,
                                                      Whpk, Wipk, bop, msgB, nullptr);

    // depth 2: msgB -> msgA
    k_atom_sum<<<asum_grid, 256, 0, stream>>>(msgB, a2b, amsg, nA);
    if (use_fbb)
        k_mfma<1, true ><<<nB / 64, 256, 0, stream>>>(fa, fb, fbb, amsg, msgB, b2a, b2revb,
                                                      Whpk, Wipk, bop, msgA, nullptr);
    else
        k_mfma<1, false><<<nB / 64, 256, 0, stream>>>(fa, fb, fbb, amsg, msgB, b2a, b2revb,
                                                      Whpk, Wipk, bop, msgA, nullptr);

    // readout
    k_atom_sum<<<asum_grid, 256, 0, stream>>>(msgA, a2b, amsg, nA);
    k_mfma<2, false><<<nA / 64, 256, 0, stream>>>(fa, fb, nullptr, amsg, nullptr, nullptr, nullptr,
                                                  Wopk, Wipk, bop, nullptr, ah);
    k_pool<<<(n_mols * 300 + 255) / 256, 256, 0, stream>>>(ah, out, n_mols, apm);
}

// Round 5
// 1941.475 us; speedup vs baseline: 1.4256x; 1.4256x over previous
//
#include <hip/hip_runtime.h>
#include <hip/hip_bf16.h>
#include <cstdint>
#include <cstddef>

#define HP 320   // padded hidden/N dim (300 -> 320)

typedef unsigned short ushortT;
typedef __attribute__((ext_vector_type(8))) __bf16 bf16x8;
typedef __attribute__((ext_vector_type(4))) float f32x4;

__device__ __forceinline__ float b2f(unsigned u) {
    union { unsigned i; float f; } v; v.i = u << 16; return v.f;
}
__device__ __forceinline__ ushortT f2b(float f) {
    union { float f; unsigned i; } v; v.f = f;
    unsigned x = v.i;
    return (ushortT)((x + 0x7fffu + ((x >> 16) & 1u)) >> 16);
}
__device__ __forceinline__ unsigned subpk(unsigned a, unsigned r) {
    union { unsigned i; float f; } al, ah, rl, rh;
    al.i = a << 16; ah.i = a & 0xffff0000u;
    rl.i = r << 16; rh.i = r & 0xffff0000u;
    float lo = al.f - rl.f, hi = ah.f - rh.f;
    return (unsigned)f2b(lo) | ((unsigned)f2b(hi) << 16);
}
__device__ __forceinline__ uint4 subpk4(uint4 a, uint4 r) {
    uint4 o;
    o.x = subpk(a.x, r.x); o.y = subpk(a.y, r.y);
    o.z = subpk(a.z, r.z); o.w = subpk(a.w, r.w);
    return o;
}

// ---------------------------------------------------------------- pack weights into MFMA B-fragment order
// packed[kt][nt(20)][kg(4)][col(16)][j(8)]  ==  W[kt*32+kg*8+j][nt*16+col]
__device__ __forceinline__ void pack_one(int idx, const float* __restrict__ W,
                                         int Ksrc, ushortT* __restrict__ dst) {
    int j = idx & 7, col = (idx >> 3) & 15, kg = (idx >> 7) & 3;
    int t = idx >> 9; int nt = t % 20, kt = t / 20;
    int k = kt * 32 + kg * 8 + j, n = nt * 16 + col;
    float v = (k < Ksrc && n < 300) ? W[k * 300 + n] : 0.f;
    dst[idx] = f2b(v);
}
// W_o remap: logical k<133 -> fa rows (src k), k in [160,460) -> amsg rows (src k-27), else 0
__device__ __forceinline__ void pack_wo(int idx, const float* __restrict__ W,
                                        ushortT* __restrict__ dst) {
    int j = idx & 7, col = (idx >> 3) & 15, kg = (idx >> 7) & 3;
    int t = idx >> 9; int nt = t % 20, kt = t / 20;
    int k = kt * 32 + kg * 8 + j, n = nt * 16 + col;
    int src = (k < 133) ? k : ((k >= 160 && k < 460) ? (k - 27) : -1);
    float v = (src >= 0 && n < 300) ? W[src * 300 + n] : 0.f;
    dst[idx] = f2b(v);
}

__global__ __launch_bounds__(256) void k_pack_weights(
    const float* __restrict__ Wi, const float* __restrict__ Wh,
    const float* __restrict__ Wo, const float* __restrict__ bo,
    ushortT* __restrict__ Wipk, ushortT* __restrict__ Whpk,
    ushortT* __restrict__ Wopk, float* __restrict__ bop) {
    int idx = blockIdx.x * 256 + threadIdx.x;
    if (idx < 51200)  pack_one(idx, Wi, 147, Wipk);   // K1 = 160 (5 ktiles)
    if (idx < 102400) pack_one(idx, Wh, 300, Whpk);   // K2 = 320 (10 ktiles)
    if (idx < 153600) pack_wo(idx, Wo, Wopk);         // K3 = 480 (15 ktiles)
    if (idx < HP) bop[idx] = (idx < 300) ? bo[idx] : 0.f;
}

// ---------------------------------------------------------------- pre-pack f_bonds -> bf16 [nB][160]
__global__ __launch_bounds__(256) void k_pack_fb(
    const float* __restrict__ fb, ushortT* __restrict__ fbb, int nB) {
    int t = blockIdx.x * 256 + threadIdx.x;
    if (t >= nB * 20) return;
    int row = t / 20, q = t - row * 20;
    int k0 = q * 8;
    union { ushortT u[8]; uint4 v; } o;
#pragma unroll
    for (int j = 0; j < 8; j++) {
        int k = k0 + j;
        o.u[j] = (k < 147) ? f2b(fb[(size_t)row * 147 + k]) : (ushortT)0;
    }
    *(uint4*)(fbb + (size_t)row * 160 + k0) = o.v;
}

// ---------------------------------------------------------------- unified MFMA GEMM, panel-staged, barrier-free K-loop
// MODE 0: A = fbb (K=160).                     out: msg = relu(A@Wi)            bf16
// MODE 1: A = [amsg[b2a]-msg[b2revb] | fbb] (K=480), B = [Whpk | Wipk].
//         out: msg = relu(diff@Wh + fb@Wi)                                      bf16
// MODE 2: A = [fa | amsg] (K=480), B = Wopk.   out: ah = relu(A@Wo + bias)      bf16
template <int MODE, bool FBB>
__global__ __launch_bounds__(256, 2) void k_mfma(
    const float* __restrict__ fa, const float* __restrict__ fb,
    const ushortT* __restrict__ fbb,
    const ushortT* __restrict__ amsg, const ushortT* __restrict__ msgin,
    const int* __restrict__ b2a, const int* __restrict__ b2revb,
    const ushortT* __restrict__ Bpk1, const ushortT* __restrict__ Bpk2,
    const float* __restrict__ bop,
    ushortT* __restrict__ outp) {
    constexpr int KT = (MODE == 0) ? 5 : 15;     // ktiles
    constexpr int SPLIT = (MODE == 1) ? 10 : KT; // B source switch point
    constexpr int KP = KT * 32;                  // panel K
    constexpr int SP = KP + 8;                   // padded row stride (ushorts): 168 / 488
    constexpr int CH = KP / 8;                   // 16B chunks per row: 20 / 60
    __shared__ __align__(16) ushortT panel[64 * SP];   // 21.5 KB / 62.5 KB

    const int tid = threadIdx.x, wave = tid >> 6, lane = tid & 63;
    const int row0 = blockIdx.x * 64;
    const int wm = wave >> 1, wn = wave & 1;

    // ================= A-panel staging: coalesced row bursts, each row touched once
#pragma unroll
    for (int it = 0; it < CH / 4; it++) {        // 64*CH/256 iterations
        int flat = tid + 256 * it;
        int row = flat / CH, ch = flat - row * CH;
        uint4 v;
        if (MODE == 1) {
            if (ch < 40) {
                size_t oa = (size_t)b2a[row0 + row] * HP;
                size_t orv = (size_t)b2revb[row0 + row] * HP;
                uint4 ua = *(const uint4*)(amsg + oa + ch * 8);
                uint4 ur = *(const uint4*)(msgin + orv + ch * 8);
                v = subpk4(ua, ur);
            } else if (FBB) {
                v = *(const uint4*)(fbb + (size_t)(row0 + row) * 160 + (ch - 40) * 8);
            } else {
                union { ushortT u[8]; uint4 w; } t;
#pragma unroll
                for (int j = 0; j < 8; j++) {
                    int k = (ch - 40) * 8 + j;
                    t.u[j] = (k < 147) ? f2b(fb[(size_t)(row0 + row) * 147 + k]) : (ushortT)0;
                }
                v = t.w;
            }
        } else if (MODE == 2) {
            if (ch >= 20) {
                v = *(const uint4*)(amsg + (size_t)(row0 + row) * HP + (ch - 20) * 8);
            } else {
                union { ushortT u[8]; uint4 w; } t;
#pragma unroll
                for (int j = 0; j < 8; j++) {
                    int k = ch * 8 + j;
                    t.u[j] = (k < 133) ? f2b(fa[(size_t)(row0 + row) * 133 + k]) : (ushortT)0;
                }
                v = t.w;
            }
        } else {  // MODE 0
            if (FBB) {
                v = *(const uint4*)(fbb + (size_t)(row0 + row) * 160 + ch * 8);
            } else {
                union { ushortT u[8]; uint4 w; } t;
#pragma unroll
                for (int j = 0; j < 8; j++) {
                    int k = ch * 8 + j;
                    t.u[j] = (k < 147) ? f2b(fb[(size_t)(row0 + row) * 147 + k]) : (ushortT)0;
                }
                v = t.w;
            }
        }
        *(uint4*)&panel[row * SP + ch * 8] = v;
    }
    __syncthreads();   // only block barrier

    // ================= barrier-free K-loop: B L2->reg (dbuf), A from LDS
    f32x4 acc[2][10];
#pragma unroll
    for (int i = 0; i < 2; i++)
#pragma unroll
        for (int n = 0; n < 10; n++) acc[i][n] = (f32x4){0.f, 0.f, 0.f, 0.f};

    uint4 breg[2][10];
    const int boff = (wn * 10) * 512 + ((lane >> 4) & 3) * 128 + (lane & 15) * 8;

#define LOADB(kt, buf)                                                              \
    {                                                                               \
        const ushortT* bp = ((kt) < SPLIT) ? (Bpk1 + (size_t)(kt) * 10240)          \
                                           : (Bpk2 + (size_t)((kt) - SPLIT) * 10240);\
        _Pragma("unroll")                                                           \
        for (int n = 0; n < 10; n++)                                                \
            breg[buf][n] = *(const uint4*)(bp + boff + n * 512);                    \
    }

    LOADB(0, 0);
    const int arow = (wm * 32 + (lane & 15)) * SP;
#pragma unroll
    for (int kt = 0; kt < KT; kt++) {
        if (kt + 1 < KT) LOADB(kt + 1, (kt + 1) & 1);
        const int k0 = kt * 32 + ((lane >> 4) & 3) * 8;
        bf16x8 a0 = *(bf16x8*)&panel[arow + k0];
        bf16x8 a1 = *(bf16x8*)&panel[arow + 16 * SP + k0];
#pragma unroll
        for (int n = 0; n < 10; n++) {
            bf16x8 b;
            *(uint4*)&b = breg[kt & 1][n];
            // swapped operands: acc holds C^T fragments
            acc[0][n] = __builtin_amdgcn_mfma_f32_16x16x32_bf16(b, a0, acc[0][n], 0, 0, 0);
            acc[1][n] = __builtin_amdgcn_mfma_f32_16x16x32_bf16(b, a1, acc[1][n], 0, 0, 0);
        }
    }
#undef LOADB

    // ================= epilogue: lane holds C[row = lane&15 (+16i)][cols (lane>>4)*4 + r + n*16]
#pragma unroll
    for (int i = 0; i < 2; i++) {
        size_t gr = (size_t)(row0 + wm * 32 + i * 16 + (lane & 15));
#pragma unroll
        for (int n = 0; n < 10; n++) {
            int col = wn * 160 + n * 16 + ((lane >> 4) & 3) * 4;
            float4 v = make_float4(acc[i][n][0], acc[i][n][1], acc[i][n][2], acc[i][n][3]);
            if (MODE == 2) {
                float4 bias = *(const float4*)&bop[col];
                v.x += bias.x; v.y += bias.y; v.z += bias.z; v.w += bias.w;
            }
            ushort4 u;
            u.x = f2b(fmaxf(v.x, 0.f)); u.y = f2b(fmaxf(v.y, 0.f));
            u.z = f2b(fmaxf(v.z, 0.f)); u.w = f2b(fmaxf(v.w, 0.f));
            *(ushort4*)&outp[gr * HP + col] = u;
        }
    }
}

// ---------------------------------------------------------------- atom sum (bf16 in/out, fp32 accum)
__global__ __launch_bounds__(256) void k_atom_sum(
    const ushortT* __restrict__ msg, const int* __restrict__ a2b,
    ushortT* __restrict__ amsg, int nA) {
    int t = blockIdx.x * 256 + threadIdx.x;
    int a = t / 40, q = t - a * 40;
    if (a >= nA) return;
    float s[8];
#pragma unroll
    for (int e = 0; e < 8; e++) s[e] = 0.f;
#pragma unroll
    for (int j = 0; j < 6; j++) {
        int b = a2b[a * 6 + j];
        uint4 u = *(const uint4*)(msg + (size_t)b * HP + q * 8);
        s[0] += b2f(u.x & 0xffff); s[1] += b2f(u.x >> 16);
        s[2] += b2f(u.y & 0xffff); s[3] += b2f(u.y >> 16);
        s[4] += b2f(u.z & 0xffff); s[5] += b2f(u.z >> 16);
        s[6] += b2f(u.w & 0xffff); s[7] += b2f(u.w >> 16);
    }
    uint4 o;
    o.x = (unsigned)f2b(s[0]) | ((unsigned)f2b(s[1]) << 16);
    o.y = (unsigned)f2b(s[2]) | ((unsigned)f2b(s[3]) << 16);
    o.z = (unsigned)f2b(s[4]) | ((unsigned)f2b(s[5]) << 16);
    o.w = (unsigned)f2b(s[6]) | ((unsigned)f2b(s[7]) << 16);
    *(uint4*)(amsg + (size_t)a * HP + q * 8) = o;
}

// ---------------------------------------------------------------- mean pool (bf16 ah -> fp32 out), vectorized
__global__ __launch_bounds__(256) void k_pool(
    const ushortT* __restrict__ ah, float* __restrict__ out, int n_mols, int apm) {
    int t = blockIdx.x * 256 + threadIdx.x;
    int m = t / 75, c4 = t - m * 75;    // 75 float4-chunks of 300 cols
    if (m >= n_mols) return;
    float4 s = make_float4(0, 0, 0, 0);
    for (int u = 0; u < apm; u++) {
        ushort4 q = *(const ushort4*)&ah[(size_t)(m * apm + u) * HP + c4 * 4];
        s.x += b2f(q.x); s.y += b2f(q.y); s.z += b2f(q.z); s.w += b2f(q.w);
    }
    float inv = 1.0f / (float)apm;
    s.x *= inv; s.y *= inv; s.z *= inv; s.w *= inv;
    *(float4*)&out[(size_t)m * 300 + c4 * 4] = s;
}

// ---------------------------------------------------------------- launch
extern "C" void kernel_launch(void* const* d_in, const int* in_sizes, int n_in,
                              void* d_out, int out_size, void* d_ws, size_t ws_size,
                              hipStream_t stream) {
    const float* fa     = (const float*)d_in[0];
    const float* fb     = (const float*)d_in[1];
    const int*   a2b    = (const int*)d_in[2];
    const int*   b2a    = (const int*)d_in[3];
    const int*   b2revb = (const int*)d_in[4];
    const float* Wi     = (const float*)d_in[5];
    const float* Wh     = (const float*)d_in[6];
    const float* Wo     = (const float*)d_in[7];
    const float* bo     = (const float*)d_in[8];

    const int nA     = in_sizes[0] / 133;   // 200000
    const int nB     = in_sizes[1] / 147;   // 400000
    const int n_mols = out_size / 300;      // 10000
    const int apm    = nA / n_mols;         // 20

    char* p = (char*)d_ws;
    ushortT* Wipk = (ushortT*)p;  p += (size_t)51200 * 2;
    ushortT* Whpk = (ushortT*)p;  p += (size_t)102400 * 2;
    ushortT* Wopk = (ushortT*)p;  p += (size_t)153600 * 2;
    float*   bop  = (float*)p;    p += (size_t)HP * 4;
    p = (char*)(((uintptr_t)p + 255) & ~(uintptr_t)255);

    const size_t msgBytes  = (size_t)nB * HP * 2;
    const size_t amsgBytes = (size_t)nA * HP * 2;
    const size_t fbbBytes  = (size_t)nB * 160 * 2;
    const size_t headBytes = (size_t)(p - (char*)d_ws);
    const bool use_fbb = ws_size >= headBytes + 2 * msgBytes + amsgBytes + fbbBytes;

    ushortT* msgA = (ushortT*)p;  p += msgBytes;
    ushortT* msgB = (ushortT*)p;  p += msgBytes;
    ushortT* amsg = (ushortT*)p;  p += amsgBytes;
    ushortT* fbb  = use_fbb ? (ushortT*)p : nullptr;
    ushortT* ah   = msgB;           // msgB dead after depth-2 GEMM consumes it
    float*   out  = (float*)d_out;

    k_pack_weights<<<600, 256, 0, stream>>>(Wi, Wh, Wo, bo, Wipk, Whpk, Wopk, bop);
    if (use_fbb)
        k_pack_fb<<<(nB * 20 + 255) / 256, 256, 0, stream>>>(fb, fbb, nB);

    const int asum_grid = (int)(((size_t)nA * 40 + 255) / 256);

    // GEMM1: msgA = relu(fb @ Wi)
    if (use_fbb)
        k_mfma<0, true ><<<nB / 64, 256, 0, stream>>>(fa, fb, fbb, nullptr, nullptr, nullptr, nullptr,
                                                      Wipk, Wipk, bop, msgA);
    else
        k_mfma<0, false><<<nB / 64, 256, 0, stream>>>(fa, fb, fbb, nullptr, nullptr, nullptr, nullptr,
                                                      Wipk, Wipk, bop, msgA);

    // depth 1: msgA -> msgB
    k_atom_sum<<<asum_grid, 256, 0, stream>>>(msgA, a2b, amsg, nA);
    if (use_fbb)
        k_mfma<1, true ><<<nB / 64, 256, 0, stream>>>(fa, fb, fbb, amsg, msgA, b2a, b2revb,
                                                      Whpk, Wipk, bop, msgB);
    else
        k_mfma<1, false><<<nB / 64, 256, 0, stream>>>(fa, fb, fbb, amsg, msgA, b2a, b2revb,
                                                      Whpk, Wipk, bop, msgB);

    // depth 2: msgB -> msgA
    k_atom_sum<<<asum_grid, 256, 0, stream>>>(msgB, a2b, amsg, nA);
    if (use_fbb)
        k_mfma<1, true ><<<nB / 64, 256, 0, stream>>>(fa, fb, fbb, amsg, msgB, b2a, b2revb,
                                                      Whpk, Wipk, bop, msgA);
    else
        k_mfma<1, false><<<nB / 64, 256, 0, stream>>>(fa, fb, fbb, amsg, msgB, b2a, b2revb,
                                                      Whpk, Wipk, bop, msgA);

    // readout: ah(bf16) = relu(concat @ Wo + b)
    k_atom_sum<<<asum_grid, 256, 0, stream>>>(msgA, a2b, amsg, nA);
    k_mfma<2, false><<<nA / 64, 256, 0, stream>>>(fa, fb, nullptr, amsg, nullptr, nullptr, nullptr,
                                                  Wopk, Wopk, bop, ah);
    k_pool<<<((n_mols * 75) + 255) / 256, 256, 0, stream>>>(ah, out, n_mols, apm);
}